// Round 10
// baseline (85.336 us; speedup 1.0000x reference)
//
#include <hip/hip_runtime.h>
#include <stdint.h>

#define DIM     300
#define NBATCH  4096
#define NSUP    64      // N*S = 2*32 support cols
#define KP      320     // B K padded to 10*32
#define ASTRIDE 328     // A LDS row stride in ushorts (8B-aligned rows)
#define SMST    82      // padded sm tile x-stride (floats)
#define SMY     36      // per-channel y extent
#define GRID_G  512     // gemm blocks: exactly 2 resident per CU
#define PPB     8       // batch panels per gemm block

typedef float f32x4 __attribute__((ext_vector_type(4)));
typedef short s16x8 __attribute__((ext_vector_type(8)));

static __device__ __forceinline__ unsigned bc(float x) { return __builtin_bit_cast(unsigned, x); }
static __device__ __forceinline__ float asf(unsigned u) { return __builtin_bit_cast(float, u); }
static __device__ __forceinline__ unsigned perm_hi(unsigned a, unsigned b) {
    return __builtin_amdgcn_perm(a, b, 0x07060302u);   // [a.hi16 : b.hi16]
}
static __device__ __forceinline__ unsigned short f2bf(float x) {   // RNE (prep only)
    unsigned u = bc(x);
    return (unsigned short)((u + 0x7FFFu + ((u >> 16) & 1u)) >> 16);
}
static __device__ __forceinline__ float bf2f(unsigned short h) { return asf((unsigned)h << 16); }

// ---------------- kernel 1: normalize support vectors -> bf16 hi/lo [64][320]
__global__ __launch_bounds__(64) void prep_kernel(
    const int* __restrict__ sidx, const float* __restrict__ emb,
    unsigned short* __restrict__ Bh, unsigned short* __restrict__ Bl) {
    const int j = blockIdx.x, l = threadIdx.x;
    const size_t tok = (size_t)sidx[j];
    const float* src = emb + tok * DIM;
    float e[5];
    #pragma unroll
    for (int c = 0; c < 5; ++c) {
        const int k = c * 64 + l;
        e[c] = (k < DIM) ? src[k] : 0.f;
    }
    float s = e[0]*e[0] + e[1]*e[1] + e[2]*e[2] + e[3]*e[3] + e[4]*e[4];
    #pragma unroll
    for (int m = 32; m >= 1; m >>= 1) s += __shfl_xor(s, m);
    const float rn = 1.f / fmaxf(sqrtf(s), 1e-8f);
    #pragma unroll
    for (int c = 0; c < 5; ++c) {
        const int k = c * 64 + l;
        const float v = (k < DIM) ? e[c] * rn : 0.f;
        const unsigned short h = f2bf(v);
        Bh[j * KP + k] = h;
        Bl[j * KP + k] = f2bf(v - bf2f(h));
    }
}

// ---------------- kernel 2: gather-GEMM; staging converts f32 -> split-bf16 LDS;
// MFMA loop is pure ds_read + L2-B + MFMA; norms via Gram MFMA.
// CRITICAL ORDERING: next-panel gathers are issued AFTER the MFMA loop (pinned by
// sched_barrier) so in-loop B-load vmcnt waits never drain older HBM gathers.
__global__ __launch_bounds__(512, 4) void gemm_kernel(
    const int* __restrict__ tokens, const float* __restrict__ emb,
    const unsigned short* __restrict__ Bh, const unsigned short* __restrict__ Bl,
    float* __restrict__ smG) {

    __shared__ __attribute__((aligned(16))) unsigned short Ah[32 * ASTRIDE];
    __shared__ __attribute__((aligned(16))) unsigned short Al[32 * ASTRIDE];
    __shared__ __attribute__((aligned(16))) float norms[32];

    const int tid = threadIdx.x;
    const int l = tid & 63;
    const int w = tid >> 6;
    const int c = l & 15, hq = l >> 4;
    const int rb = (w >> 2) * 16;
    const int cg = w & 3;
    const int chn = cg >> 1, sb = (cg & 1) * 16;
    const int bbase = blockIdx.x * PPB;

    // zero the K-pad (k=300..319) once; never rewritten by staging
    if (tid < 448) {
        const int row = tid / 14, q = tid - 14 * row;   // 14 uints cover 28 ushorts
        ((unsigned*)Ah)[row * 164 + 150 + q] = 0u;
        ((unsigned*)Al)[row * 164 + 150 + q] = 0u;
    }

    // static staging chunk map: chunk ci = tid + 512*m over [32 rows][75 float4s]
    const int ci1 = tid + 512, ci2 = tid + 1024, ci3 = tid + 1536, ci4 = tid + 2048;
    const int r0 = tid / 75, j0 = tid - 75 * r0;
    const int r1 = ci1 / 75, j1 = ci1 - 75 * r1;
    const int r2 = ci2 / 75, j2 = ci2 - 75 * r2;
    const int r3 = ci3 / 75, j3 = ci3 - 75 * r3;
    const int r4 = ci4 / 75, j4 = ci4 - 75 * r4;
    const bool has4 = (ci4 < 2400);

    const unsigned short* pBh = Bh + (cg * 16 + c) * KP + hq * 8;
    const unsigned short* pBl = Bl + (cg * 16 + c) * KP + hq * 8;
    const int abase = (rb + c) * ASTRIDE + hq * 8;

    float4 st0, st1, st2, st3, st4;

    // prologue: gather panel 0
    {
        const int tb = bbase * 32;
        st0 = *(const float4*)(emb + (size_t)tokens[tb + r0] * DIM + j0 * 4);
        st1 = *(const float4*)(emb + (size_t)tokens[tb + r1] * DIM + j1 * 4);
        st2 = *(const float4*)(emb + (size_t)tokens[tb + r2] * DIM + j2 * 4);
        st3 = *(const float4*)(emb + (size_t)tokens[tb + r3] * DIM + j3 * 4);
        if (has4) st4 = *(const float4*)(emb + (size_t)tokens[tb + r4] * DIM + j4 * 4);
    }

    // convert one float4 chunk -> 4 bf16 hi + 4 bf16 lo, store to LDS
    #define STORE_CHUNK(ST, R, J)                                                   \
    {                                                                               \
        const unsigned u0 = bc(ST.x) + 0x8000u, u1 = bc(ST.y) + 0x8000u;            \
        const unsigned u2 = bc(ST.z) + 0x8000u, u3 = bc(ST.w) + 0x8000u;            \
        const float q0f = ST.x - asf(u0 & 0xffff0000u);                             \
        const float q1f = ST.y - asf(u1 & 0xffff0000u);                             \
        const float q2f = ST.z - asf(u2 & 0xffff0000u);                             \
        const float q3f = ST.w - asf(u3 & 0xffff0000u);                             \
        *(uint2*)(&Ah[(R) * ASTRIDE + (J) * 4]) =                                   \
            uint2{perm_hi(u1, u0), perm_hi(u3, u2)};                                \
        *(uint2*)(&Al[(R) * ASTRIDE + (J) * 4]) =                                   \
            uint2{perm_hi(bc(q1f) + 0x8000u, bc(q0f) + 0x8000u),                    \
                  perm_hi(bc(q3f) + 0x8000u, bc(q2f) + 0x8000u)};                   \
    }

    STORE_CHUNK(st0, r0, j0); STORE_CHUNK(st1, r1, j1); STORE_CHUNK(st2, r2, j2);
    STORE_CHUNK(st3, r3, j3);
    if (has4) STORE_CHUNK(st4, r4, j4);
    __syncthreads();

    #pragma unroll 1
    for (int p = 0; p < PPB; ++p) {
        // pure MFMA loop: LDS-A fragments x L2-B fragments + Gram norms.
        // No older HBM loads outstanding -> B-load waits are pure L2 latency.
        f32x4 q0 = {0,0,0,0}, q1 = {0,0,0,0}, q2 = {0,0,0,0};
        f32x4 gv = {0,0,0,0}, g2 = {0,0,0,0};
        #pragma unroll
        for (int t = 0; t < 10; ++t) {
            const s16x8 ah = *(const s16x8*)(Ah + abase + t * 32);
            const s16x8 al = *(const s16x8*)(Al + abase + t * 32);
            const s16x8 bh = *(const s16x8*)(pBh + t * 32);
            const s16x8 bl = *(const s16x8*)(pBl + t * 32);
            q0 = __builtin_amdgcn_mfma_f32_16x16x32_bf16(ah, bh, q0, 0, 0, 0);
            q1 = __builtin_amdgcn_mfma_f32_16x16x32_bf16(ah, bl, q1, 0, 0, 0);
            q2 = __builtin_amdgcn_mfma_f32_16x16x32_bf16(al, bh, q2, 0, 0, 0);
            gv = __builtin_amdgcn_mfma_f32_16x16x32_bf16(ah, ah, gv, 0, 0, 0);
            g2 = __builtin_amdgcn_mfma_f32_16x16x32_bf16(ah, al, g2, 0, 0, 0);
        }

        // diagonal lanes own |row rb+c|^2 (4 col-group waves race: identical values)
        if (hq == (c >> 2)) {
            const int q = c & 3;
            const float d1 = (q == 0) ? gv[0] : (q == 1) ? gv[1] : (q == 2) ? gv[2] : gv[3];
            const float d2 = (q == 0) ? g2[0] : (q == 1) ? g2[1] : (q == 2) ? g2[2] : g2[3];
            norms[rb + c] = d1 + 2.f * d2;
        }
        asm volatile("s_waitcnt lgkmcnt(0)" ::: "memory");   // intra-wave write->read
        const f32x4 n4 = *(const f32x4*)&norms[rb + hq * 4];
        float4 vv;
        #pragma unroll
        for (int q = 0; q < 4; ++q) {
            const float rn = __builtin_amdgcn_rcpf(
                fmaxf(__builtin_amdgcn_sqrtf(n4[q]), 1e-8f));
            ((float*)&vv)[q] = (q0[q] + q1[q] + q2[q]) * rn;
        }
        // coalesced sm store [b][ch][s][r]
        *(float4*)(smG + ((size_t)((bbase + p) * 2 + chn) * 32 + sb + c) * 32 + rb + hq * 4) = vv;

        if (p < PPB - 1) {
            // pin: gathers must be issued AFTER all loop B-loads (younger in vmcnt queue)
            __builtin_amdgcn_sched_barrier(0);
            const int tb = (bbase + p + 1) * 32;
            st0 = *(const float4*)(emb + (size_t)tokens[tb + r0] * DIM + j0 * 4);
            st1 = *(const float4*)(emb + (size_t)tokens[tb + r1] * DIM + j1 * 4);
            st2 = *(const float4*)(emb + (size_t)tokens[tb + r2] * DIM + j2 * 4);
            st3 = *(const float4*)(emb + (size_t)tokens[tb + r3] * DIM + j3 * 4);
            if (has4) st4 = *(const float4*)(emb + (size_t)tokens[tb + r4] * DIM + j4 * 4);
            __syncthreads();    // all waves done reading A (drains gathers too)
            STORE_CHUNK(st0, r0, j0); STORE_CHUNK(st1, r1, j1); STORE_CHUNK(st2, r2, j2);
            STORE_CHUNK(st3, r3, j3);
            if (has4) STORE_CHUNK(st4, r4, j4);
            __syncthreads();    // next panel ready
        }
    }
    #undef STORE_CHUNK
}

// ---------------- kernel 3: tail per batch (softmax-gate + conv1 + conv2 + fc)
__global__ __launch_bounds__(256) void tail_kernel(
    const float* __restrict__ smG,
    const float* __restrict__ c1w, const float* __restrict__ c1b,
    const float* __restrict__ c2w, const float* __restrict__ c2b,
    const float* __restrict__ f2w, const float* __restrict__ f2b,
    const float* __restrict__ fcw, const float* __restrict__ fcb,
    float* __restrict__ out) {

    __shared__ __attribute__((aligned(16))) float smP[34 * SMST];  // [xp=r+1][ch][yp=s+1]
    __shared__ __attribute__((aligned(16))) float pl1P[2 * 17 * 18];
    __shared__ float scrP[8];    // [0..3]=se_w, [4..7]=sv_w

    const int tid = threadIdx.x;
    const int w = tid >> 6, l = tid & 63;
    const int b = blockIdx.x;

    // P0: zero smP + pl1 borders
    {
        const f32x4 z = {0.f, 0.f, 0.f, 0.f};
        #pragma unroll
        for (int i = 0; i < 3; ++i) {
            const int idx = i * 256 + tid;
            if (idx < 697) ((f32x4*)smP)[idx] = z;
        }
        if (tid >= 190) {
            const int z2 = tid - 190;
            const int ic = (z2 >= 33) ? 1 : 0;
            const int rm = z2 - 33 * ic;
            pl1P[ic * 306 + (rm < 17 ? rm : (rm - 16) * 18)] = 0.f;
        }
    }
    __syncthreads();

    // P1: load sm (coalesced) -> padded LDS + fused softmax partials
    {
        const float* src = smG + (size_t)b * 2048;
        float se = 0.f, sv = 0.f;
        #pragma unroll
        for (int h2 = 0; h2 < 2; ++h2) {
            const int f4 = tid * 2 + h2;            // waves 0-1: ch0; waves 2-3: ch1
            const float4 v = ((const float4*)src)[f4];
            const int base = f4 * 4;
            const int chn = base >> 10;
            const int s = (base >> 5) & 31;
            const int r = base & 31;
            float* dstp = &smP[(r + 1) * SMST + chn * SMY + (s + 1)];
            dstp[0] = v.x; dstp[SMST] = v.y; dstp[2 * SMST] = v.z; dstp[3 * SMST] = v.w;
            const float e0 = __expf(v.x), e1 = __expf(v.y);   // |v|<=1: no max-shift
            const float e2 = __expf(v.z), e3 = __expf(v.w);
            se += e0 + e1 + e2 + e3;
            sv = fmaf(e0, v.x, sv); sv = fmaf(e1, v.y, sv);
            sv = fmaf(e2, v.z, sv); sv = fmaf(e3, v.w, sv);
        }
        #pragma unroll
        for (int m = 32; m >= 1; m >>= 1) { se += __shfl_xor(se, m); sv += __shfl_xor(sv, m); }
        if (l == 0) { scrP[w] = se; scrP[4 + w] = sv; }
    }
    __syncthreads();

    // P2: conv1 (both oc per thread) + gate + relu + maxpool -> pl1P
    {
        const int ii = tid >> 4, jj = tid & 15;
        float pc0[4] = {0,0,0,0}, pc1[4] = {0,0,0,0};
        float pA0[4] = {0,0,0,0}, pA1[4] = {0,0,0,0};
        #pragma unroll
        for (int ic = 0; ic < 2; ++ic) {
            float p[4][4];
            #pragma unroll
            for (int a = 0; a < 4; ++a) {        // xp = 2jj+a, yp base 2ii
                const int off = (2 * jj + a) * SMST + ic * SMY + 2 * ii;
                const float2 v01 = *(const float2*)&smP[off];
                const float2 v23 = *(const float2*)&smP[off + 2];
                p[a][0] = v01.x; p[a][1] = v01.y; p[a][2] = v23.x; p[a][3] = v23.y;
            }
            #pragma unroll
            for (int py = 0; py < 2; ++py)
            #pragma unroll
            for (int px = 0; px < 2; ++px)
            #pragma unroll
            for (int dy = 0; dy < 3; ++dy)
            #pragma unroll
            for (int dx = 0; dx < 3; ++dx) {
                const float pv = p[px + dx][py + dy];
                const int pos = py * 2 + px;
                if (ic == 0) {
                    pc0[pos] = fmaf(c1w[0 * 9 + dy * 3 + dx], pv, pc0[pos]);
                    pc1[pos] = fmaf(c1w[2 * 9 + dy * 3 + dx], pv, pc1[pos]);
                } else {
                    pA0[pos] = fmaf(c1w[1 * 9 + dy * 3 + dx], pv, pA0[pos]);
                    pA1[pos] = fmaf(c1w[3 * 9 + dy * 3 + dx], pv, pA1[pos]);
                }
            }
        }
        const float p0 = (scrP[4] + scrP[5]) / (scrP[0] + scrP[1]);
        const float p1 = (scrP[6] + scrP[7]) / (scrP[2] + scrP[3]);
        const float gg0 = 1.f / (1.f + __expf(-(f2w[0] * p0 + f2w[1] * p1 + f2b[0])));
        const float gg1 = 1.f / (1.f + __expf(-(f2w[2] * p0 + f2w[3] * p1 + f2b[1])));
        const float b0 = c1b[0], b1 = c1b[1];
        float mx0 = 0.f, mx1 = 0.f;   // relu folded
        #pragma unroll
        for (int i = 0; i < 4; ++i) {
            mx0 = fmaxf(mx0, b0 + gg0 * pc0[i] + gg1 * pA0[i]);
            mx1 = fmaxf(mx1, b1 + gg0 * pc1[i] + gg1 * pA1[i]);
        }
        pl1P[0 * 306 + (ii + 1) * 18 + (jj + 1)] = mx0;
        pl1P[1 * 306 + (ii + 1) * 18 + (jj + 1)] = mx1;
    }
    __syncthreads();

    // P3: wave 0: conv2(2x2,pad1)+relu+avgpool2 + fc -> out
    if (w == 0) {
        float o0 = 0.f, o1 = 0.f;
        #pragma unroll
        for (int h = 0; h < 2; ++h) {
            const int o = h * 64 + l, oc2 = o >> 6, ii2 = (o >> 3) & 7, jj2 = o & 7;
            float sum = 0.f;
            #pragma unroll
            for (int py = 0; py < 2; ++py)
            #pragma unroll
            for (int px = 0; px < 2; ++px) {
                const int y = 2 * ii2 + py, x = 2 * jj2 + px;
                float acc = c2b[oc2];
                #pragma unroll
                for (int ic = 0; ic < 2; ++ic)
                #pragma unroll
                for (int dy = 0; dy < 2; ++dy)
                #pragma unroll
                for (int dx = 0; dx < 2; ++dx)
                    acc += c2w[((oc2 * 2 + ic) * 2 + dy) * 2 + dx] *
                           pl1P[ic * 306 + (y + dy) * 18 + (x + dx)];
                sum += fmaxf(acc, 0.f);
            }
            const float val = 0.25f * sum;
            o0 = fmaf(val, fcw[o], o0);
            o1 = fmaf(val, fcw[128 + o], o1);
        }
        #pragma unroll
        for (int m = 32; m >= 1; m >>= 1) { o0 += __shfl_xor(o0, m); o1 += __shfl_xor(o1, m); }
        if (l == 0) {
            out[b * 2 + 0] = fcb[0] + o0;
            out[b * 2 + 1] = fcb[1] + o1;
        }
    }
}

extern "C" void kernel_launch(void* const* d_in, const int* in_sizes, int n_in,
                              void* d_out, int out_size, void* d_ws, size_t ws_size,
                              hipStream_t stream) {
    const int* tokens = (const int*)d_in[0];
    const int* sidx   = (const int*)d_in[1];
    const float* emb  = (const float*)d_in[2];
    const float* c1w  = (const float*)d_in[3];
    const float* c1b  = (const float*)d_in[4];
    const float* c2w  = (const float*)d_in[5];
    const float* c2b  = (const float*)d_in[6];
    const float* f2w  = (const float*)d_in[7];
    const float* f2b  = (const float*)d_in[8];
    const float* fcw  = (const float*)d_in[9];
    const float* fcb  = (const float*)d_in[10];

    // ws layout: [sm f32 4096*2*32*32 = 32 MiB][Bh 40 KiB][Bl 40 KiB]
    float* smG = (float*)d_ws;
    unsigned short* Bh = (unsigned short*)((char*)d_ws + (size_t)NBATCH * 2048 * 4);
    unsigned short* Bl = Bh + NSUP * KP;

    prep_kernel<<<NSUP, 64, 0, stream>>>(sidx, emb, Bh, Bl);
    gemm_kernel<<<GRID_G, 512, 0, stream>>>(tokens, emb, Bh, Bl, smG);
    tail_kernel<<<NBATCH, 256, 0, stream>>>(smG, c1w, c1b, c2w, c2b,
                                            f2w, f2b, fcw, fcb, (float*)d_out);
}

// Round 11
// 69.031 us; speedup vs baseline: 1.2362x; 1.2362x over previous
//
#include <hip/hip_runtime.h>
#include <stdint.h>

#define DIM     300
#define NBATCH  4096
#define NSUP    64      // N*S = 2*32 support cols
#define KP      320     // B K padded to 10*32
#define LSTR    328     // LDS row stride in ushorts for A and B tiles (656 B)
#define SMST    82      // padded sm tile x-stride (floats)
#define SMY     36      // per-channel y extent
#define GRID_G  256     // gemm blocks: 1 per CU (126 KB LDS)
#define PPB     16      // batch panels per gemm block

typedef float f32x4 __attribute__((ext_vector_type(4)));
typedef short s16x8 __attribute__((ext_vector_type(8)));

static __device__ __forceinline__ unsigned bc(float x) { return __builtin_bit_cast(unsigned, x); }
static __device__ __forceinline__ float asf(unsigned u) { return __builtin_bit_cast(float, u); }
static __device__ __forceinline__ unsigned perm_hi(unsigned a, unsigned b) {
    return __builtin_amdgcn_perm(a, b, 0x07060302u);   // [a.hi16 : b.hi16]
}
static __device__ __forceinline__ unsigned short f2bf(float x) {   // RNE (prep only)
    unsigned u = bc(x);
    return (unsigned short)((u + 0x7FFFu + ((u >> 16) & 1u)) >> 16);
}
static __device__ __forceinline__ float bf2f(unsigned short h) { return asf((unsigned)h << 16); }

// ---------------- kernel 1: normalize support vectors -> bf16 hi/lo [64][320]
__global__ __launch_bounds__(64) void prep_kernel(
    const int* __restrict__ sidx, const float* __restrict__ emb,
    unsigned short* __restrict__ Bh, unsigned short* __restrict__ Bl) {
    const int j = blockIdx.x, l = threadIdx.x;
    const size_t tok = (size_t)sidx[j];
    const float* src = emb + tok * DIM;
    float e[5];
    #pragma unroll
    for (int c = 0; c < 5; ++c) {
        const int k = c * 64 + l;
        e[c] = (k < DIM) ? src[k] : 0.f;
    }
    float s = e[0]*e[0] + e[1]*e[1] + e[2]*e[2] + e[3]*e[3] + e[4]*e[4];
    #pragma unroll
    for (int m = 32; m >= 1; m >>= 1) s += __shfl_xor(s, m);
    const float rn = 1.f / fmaxf(sqrtf(s), 1e-8f);
    #pragma unroll
    for (int c = 0; c < 5; ++c) {
        const int k = c * 64 + l;
        const float v = (k < DIM) ? e[c] * rn : 0.f;
        const unsigned short h = f2bf(v);
        Bh[j * KP + k] = h;
        Bl[j * KP + k] = f2bf(v - bf2f(h));
    }
}

// ---------------- kernel 2: persistent gather-GEMM, B resident in LDS.
// Inner MFMA loop touches ONLY LDS (lgkmcnt) -> in-flight HBM gathers (vmcnt)
// never stall it. Gathers issued BEFORE the loop, consumed AFTER the barrier.
__global__ __launch_bounds__(512) void gemm_kernel(
    const int* __restrict__ tokens, const float* __restrict__ emb,
    const unsigned short* __restrict__ Bh, const unsigned short* __restrict__ Bl,
    float* __restrict__ smG) {

    __shared__ __attribute__((aligned(16))) unsigned short AhL[32 * LSTR];  // 21 KB
    __shared__ __attribute__((aligned(16))) unsigned short AlL[32 * LSTR];  // 21 KB
    __shared__ __attribute__((aligned(16))) unsigned short BhL[NSUP * LSTR]; // 42 KB
    __shared__ __attribute__((aligned(16))) unsigned short BlL[NSUP * LSTR]; // 42 KB
    __shared__ __attribute__((aligned(16))) float norms[32];

    const int tid = threadIdx.x;
    const int l = tid & 63;
    const int w = tid >> 6;
    const int c = l & 15, hq = l >> 4;
    const int rb = (w >> 2) * 16;
    const int cg = w & 3;
    const int chn = cg >> 1, sb = (cg & 1) * 16;
    const int bbase = blockIdx.x * PPB;

    // ---- one-time: stage B [64][320] -> LDS [64][328] (5120 16B chunks, 10/thread)
    #pragma unroll
    for (int m = 0; m < 10; ++m) {
        const int ci = tid + m * 512;            // 0..5119
        const int plane = ci / 2560;
        const int rem = ci - plane * 2560;
        const int rr = rem / 40, jj = rem - rr * 40;
        const uint4 v = *(const uint4*)((plane ? Bl : Bh) + rr * KP + jj * 8);
        *(uint4*)((plane ? BlL : BhL) + rr * LSTR + jj * 8) = v;
    }
    // ---- one-time: zero A K-pad (k=300..327), never rewritten by staging
    if (tid < 448) {
        const int row = tid / 14, q = tid - 14 * row;   // 14 uints = 28 ushorts
        ((unsigned*)AhL)[row * 164 + 150 + q] = 0u;
        ((unsigned*)AlL)[row * 164 + 150 + q] = 0u;
    }

    // static staging chunk map: chunk ci = tid + 512*m over [32 rows][75 float4s]
    const int ci1 = tid + 512, ci2 = tid + 1024, ci3 = tid + 1536, ci4 = tid + 2048;
    const int r0 = tid / 75, j0 = tid - 75 * r0;
    const int r1 = ci1 / 75, j1 = ci1 - 75 * r1;
    const int r2 = ci2 / 75, j2 = ci2 - 75 * r2;
    const int r3 = ci3 / 75, j3 = ci3 - 75 * r3;
    const int r4 = ci4 / 75, j4 = ci4 - 75 * r4;
    const bool has4 = (ci4 < 2400);

    const int abase = (rb + c) * LSTR + hq * 8;
    const int bbl   = (cg * 16 + c) * LSTR + hq * 8;

    float4 st0, st1, st2, st3, st4;

    #define ISSUE_GATHER(TB)                                                        \
    {                                                                               \
        st0 = *(const float4*)(emb + (size_t)tokens[(TB) + r0] * DIM + j0 * 4);     \
        st1 = *(const float4*)(emb + (size_t)tokens[(TB) + r1] * DIM + j1 * 4);     \
        st2 = *(const float4*)(emb + (size_t)tokens[(TB) + r2] * DIM + j2 * 4);     \
        st3 = *(const float4*)(emb + (size_t)tokens[(TB) + r3] * DIM + j3 * 4);     \
        if (has4) st4 = *(const float4*)(emb + (size_t)tokens[(TB) + r4] * DIM + j4 * 4); \
    }

    // convert one float4 chunk -> 4 bf16 hi + 4 bf16 lo, store to LDS A tiles
    #define STORE_CHUNK(ST, R, J)                                                   \
    {                                                                               \
        const unsigned u0 = bc(ST.x) + 0x8000u, u1 = bc(ST.y) + 0x8000u;            \
        const unsigned u2 = bc(ST.z) + 0x8000u, u3 = bc(ST.w) + 0x8000u;            \
        const float q0f = ST.x - asf(u0 & 0xffff0000u);                             \
        const float q1f = ST.y - asf(u1 & 0xffff0000u);                             \
        const float q2f = ST.z - asf(u2 & 0xffff0000u);                             \
        const float q3f = ST.w - asf(u3 & 0xffff0000u);                             \
        *(uint2*)(&AhL[(R) * LSTR + (J) * 4]) =                                     \
            uint2{perm_hi(u1, u0), perm_hi(u3, u2)};                                \
        *(uint2*)(&AlL[(R) * LSTR + (J) * 4]) =                                     \
            uint2{perm_hi(bc(q1f) + 0x8000u, bc(q0f) + 0x8000u),                    \
                  perm_hi(bc(q3f) + 0x8000u, bc(q2f) + 0x8000u)};                   \
    }

    // prologue: gather + stage panel 0
    ISSUE_GATHER(bbase * 32);
    STORE_CHUNK(st0, r0, j0); STORE_CHUNK(st1, r1, j1); STORE_CHUNK(st2, r2, j2);
    STORE_CHUNK(st3, r3, j3);
    if (has4) STORE_CHUNK(st4, r4, j4);
    __syncthreads();   // A panel0 + B + pads all in LDS

    #pragma unroll 1
    for (int p = 0; p < PPB; ++p) {
        // issue next panel's gathers NOW: they ride vmcnt; the loop below never
        // touches vmcnt, so they overlap it fully. Pin so they can't sink.
        if (p + 1 < PPB) ISSUE_GATHER((bbase + p + 1) * 32);
        __builtin_amdgcn_sched_barrier(0);

        // pure-LDS MFMA loop + Gram norms
        f32x4 q0 = {0,0,0,0}, q1 = {0,0,0,0}, q2 = {0,0,0,0};
        f32x4 gv = {0,0,0,0}, g2 = {0,0,0,0};
        #pragma unroll
        for (int t = 0; t < 10; ++t) {
            const s16x8 ah = *(const s16x8*)(AhL + abase + t * 32);
            const s16x8 al = *(const s16x8*)(AlL + abase + t * 32);
            const s16x8 bh = *(const s16x8*)(BhL + bbl + t * 32);
            const s16x8 bl = *(const s16x8*)(BlL + bbl + t * 32);
            q0 = __builtin_amdgcn_mfma_f32_16x16x32_bf16(ah, bh, q0, 0, 0, 0);
            q1 = __builtin_amdgcn_mfma_f32_16x16x32_bf16(ah, bl, q1, 0, 0, 0);
            q2 = __builtin_amdgcn_mfma_f32_16x16x32_bf16(al, bh, q2, 0, 0, 0);
            gv = __builtin_amdgcn_mfma_f32_16x16x32_bf16(ah, ah, gv, 0, 0, 0);
            g2 = __builtin_amdgcn_mfma_f32_16x16x32_bf16(ah, al, g2, 0, 0, 0);
        }

        // diagonal lanes own |row rb+c|^2 (4 col-group waves race: identical values)
        if (hq == (c >> 2)) {
            const int q = c & 3;
            const float d1 = (q == 0) ? gv[0] : (q == 1) ? gv[1] : (q == 2) ? gv[2] : gv[3];
            const float d2 = (q == 0) ? g2[0] : (q == 1) ? g2[1] : (q == 2) ? g2[2] : g2[3];
            norms[rb + c] = d1 + 2.f * d2;
        }
        asm volatile("s_waitcnt lgkmcnt(0)" ::: "memory");   // intra-wave write->read
        const f32x4 n4 = *(const f32x4*)&norms[rb + hq * 4];
        float4 vv;
        #pragma unroll
        for (int q = 0; q < 4; ++q) {
            const float rn = __builtin_amdgcn_rcpf(
                fmaxf(__builtin_amdgcn_sqrtf(n4[q]), 1e-8f));
            ((float*)&vv)[q] = (q0[q] + q1[q] + q2[q]) * rn;
        }
        // coalesced sm store [b][ch][s][r]
        *(float4*)(smG + ((size_t)((bbase + p) * 2 + chn) * 32 + sb + c) * 32 + rb + hq * 4) = vv;

        __syncthreads();    // all waves done reading A tiles
        if (p + 1 < PPB) {
            // gathers have had the whole MFMA loop to land; vmcnt wait is cheap
            STORE_CHUNK(st0, r0, j0); STORE_CHUNK(st1, r1, j1); STORE_CHUNK(st2, r2, j2);
            STORE_CHUNK(st3, r3, j3);
            if (has4) STORE_CHUNK(st4, r4, j4);
        }
        __syncthreads();    // next panel's A tiles ready
    }
    #undef STORE_CHUNK
    #undef ISSUE_GATHER
}

// ---------------- kernel 3: tail per batch (softmax-gate + conv1 + conv2 + fc)
__global__ __launch_bounds__(256) void tail_kernel(
    const float* __restrict__ smG,
    const float* __restrict__ c1w, const float* __restrict__ c1b,
    const float* __restrict__ c2w, const float* __restrict__ c2b,
    const float* __restrict__ f2w, const float* __restrict__ f2b,
    const float* __restrict__ fcw, const float* __restrict__ fcb,
    float* __restrict__ out) {

    __shared__ __attribute__((aligned(16))) float smP[34 * SMST];  // [xp=r+1][ch][yp=s+1]
    __shared__ __attribute__((aligned(16))) float pl1P[2 * 17 * 18];
    __shared__ float scrP[8];    // [0..3]=se_w, [4..7]=sv_w

    const int tid = threadIdx.x;
    const int w = tid >> 6, l = tid & 63;
    const int b = blockIdx.x;

    // P0: zero smP + pl1 borders
    {
        const f32x4 z = {0.f, 0.f, 0.f, 0.f};
        #pragma unroll
        for (int i = 0; i < 3; ++i) {
            const int idx = i * 256 + tid;
            if (idx < 697) ((f32x4*)smP)[idx] = z;
        }
        if (tid >= 190) {
            const int z2 = tid - 190;
            const int ic = (z2 >= 33) ? 1 : 0;
            const int rm = z2 - 33 * ic;
            pl1P[ic * 306 + (rm < 17 ? rm : (rm - 16) * 18)] = 0.f;
        }
    }
    __syncthreads();

    // P1: load sm (coalesced) -> padded LDS + fused softmax partials
    {
        const float* src = smG + (size_t)b * 2048;
        float se = 0.f, sv = 0.f;
        #pragma unroll
        for (int h2 = 0; h2 < 2; ++h2) {
            const int f4 = tid * 2 + h2;            // waves 0-1: ch0; waves 2-3: ch1
            const float4 v = ((const float4*)src)[f4];
            const int base = f4 * 4;
            const int chn = base >> 10;
            const int s = (base >> 5) & 31;
            const int r = base & 31;
            float* dstp = &smP[(r + 1) * SMST + chn * SMY + (s + 1)];
            dstp[0] = v.x; dstp[SMST] = v.y; dstp[2 * SMST] = v.z; dstp[3 * SMST] = v.w;
            const float e0 = __expf(v.x), e1 = __expf(v.y);   // |v|<=1: no max-shift
            const float e2 = __expf(v.z), e3 = __expf(v.w);
            se += e0 + e1 + e2 + e3;
            sv = fmaf(e0, v.x, sv); sv = fmaf(e1, v.y, sv);
            sv = fmaf(e2, v.z, sv); sv = fmaf(e3, v.w, sv);
        }
        #pragma unroll
        for (int m = 32; m >= 1; m >>= 1) { se += __shfl_xor(se, m); sv += __shfl_xor(sv, m); }
        if (l == 0) { scrP[w] = se; scrP[4 + w] = sv; }
    }
    __syncthreads();

    // P2: conv1 (both oc per thread) + gate + relu + maxpool -> pl1P
    {
        const int ii = tid >> 4, jj = tid & 15;
        float pc0[4] = {0,0,0,0}, pc1[4] = {0,0,0,0};
        float pA0[4] = {0,0,0,0}, pA1[4] = {0,0,0,0};
        #pragma unroll
        for (int ic = 0; ic < 2; ++ic) {
            float p[4][4];
            #pragma unroll
            for (int a = 0; a < 4; ++a) {        // xp = 2jj+a, yp base 2ii
                const int off = (2 * jj + a) * SMST + ic * SMY + 2 * ii;
                const float2 v01 = *(const float2*)&smP[off];
                const float2 v23 = *(const float2*)&smP[off + 2];
                p[a][0] = v01.x; p[a][1] = v01.y; p[a][2] = v23.x; p[a][3] = v23.y;
            }
            #pragma unroll
            for (int py = 0; py < 2; ++py)
            #pragma unroll
            for (int px = 0; px < 2; ++px)
            #pragma unroll
            for (int dy = 0; dy < 3; ++dy)
            #pragma unroll
            for (int dx = 0; dx < 3; ++dx) {
                const float pv = p[px + dx][py + dy];
                const int pos = py * 2 + px;
                if (ic == 0) {
                    pc0[pos] = fmaf(c1w[0 * 9 + dy * 3 + dx], pv, pc0[pos]);
                    pc1[pos] = fmaf(c1w[2 * 9 + dy * 3 + dx], pv, pc1[pos]);
                } else {
                    pA0[pos] = fmaf(c1w[1 * 9 + dy * 3 + dx], pv, pA0[pos]);
                    pA1[pos] = fmaf(c1w[3 * 9 + dy * 3 + dx], pv, pA1[pos]);
                }
            }
        }
        const float p0 = (scrP[4] + scrP[5]) / (scrP[0] + scrP[1]);
        const float p1 = (scrP[6] + scrP[7]) / (scrP[2] + scrP[3]);
        const float gg0 = 1.f / (1.f + __expf(-(f2w[0] * p0 + f2w[1] * p1 + f2b[0])));
        const float gg1 = 1.f / (1.f + __expf(-(f2w[2] * p0 + f2w[3] * p1 + f2b[1])));
        const float b0 = c1b[0], b1 = c1b[1];
        float mx0 = 0.f, mx1 = 0.f;   // relu folded
        #pragma unroll
        for (int i = 0; i < 4; ++i) {
            mx0 = fmaxf(mx0, b0 + gg0 * pc0[i] + gg1 * pA0[i]);
            mx1 = fmaxf(mx1, b1 + gg0 * pc1[i] + gg1 * pA1[i]);
        }
        pl1P[0 * 306 + (ii + 1) * 18 + (jj + 1)] = mx0;
        pl1P[1 * 306 + (ii + 1) * 18 + (jj + 1)] = mx1;
    }
    __syncthreads();

    // P3: wave 0: conv2(2x2,pad1)+relu+avgpool2 + fc -> out
    if (w == 0) {
        float o0 = 0.f, o1 = 0.f;
        #pragma unroll
        for (int h = 0; h < 2; ++h) {
            const int o = h * 64 + l, oc2 = o >> 6, ii2 = (o >> 3) & 7, jj2 = o & 7;
            float sum = 0.f;
            #pragma unroll
            for (int py = 0; py < 2; ++py)
            #pragma unroll
            for (int px = 0; px < 2; ++px) {
                const int y = 2 * ii2 + py, x = 2 * jj2 + px;
                float acc = c2b[oc2];
                #pragma unroll
                for (int ic = 0; ic < 2; ++ic)
                #pragma unroll
                for (int dy = 0; dy < 2; ++dy)
                #pragma unroll
                for (int dx = 0; dx < 2; ++dx)
                    acc += c2w[((oc2 * 2 + ic) * 2 + dy) * 2 + dx] *
                           pl1P[ic * 306 + (y + dy) * 18 + (x + dx)];
                sum += fmaxf(acc, 0.f);
            }
            const float val = 0.25f * sum;
            o0 = fmaf(val, fcw[o], o0);
            o1 = fmaf(val, fcw[128 + o], o1);
        }
        #pragma unroll
        for (int m = 32; m >= 1; m >>= 1) { o0 += __shfl_xor(o0, m); o1 += __shfl_xor(o1, m); }
        if (l == 0) {
            out[b * 2 + 0] = fcb[0] + o0;
            out[b * 2 + 1] = fcb[1] + o1;
        }
    }
}

extern "C" void kernel_launch(void* const* d_in, const int* in_sizes, int n_in,
                              void* d_out, int out_size, void* d_ws, size_t ws_size,
                              hipStream_t stream) {
    const int* tokens = (const int*)d_in[0];
    const int* sidx   = (const int*)d_in[1];
    const float* emb  = (const float*)d_in[2];
    const float* c1w  = (const float*)d_in[3];
    const float* c1b  = (const float*)d_in[4];
    const float* c2w  = (const float*)d_in[5];
    const float* c2b  = (const float*)d_in[6];
    const float* f2w  = (const float*)d_in[7];
    const float* f2b  = (const float*)d_in[8];
    const float* fcw  = (const float*)d_in[9];
    const float* fcb  = (const float*)d_in[10];

    // ws layout: [sm f32 4096*2*32*32 = 32 MiB][Bh 40 KiB][Bl 40 KiB]
    float* smG = (float*)d_ws;
    unsigned short* Bh = (unsigned short*)((char*)d_ws + (size_t)NBATCH * 2048 * 4);
    unsigned short* Bl = Bh + NSUP * KP;

    prep_kernel<<<NSUP, 64, 0, stream>>>(sidx, emb, Bh, Bl);
    gemm_kernel<<<GRID_G, 512, 0, stream>>>(tokens, emb, Bh, Bl, smG);
    tail_kernel<<<NBATCH, 256, 0, stream>>>(smG, c1w, c1b, c2w, c2b,
                                            f2w, f2b, fcw, fcb, (float*)d_out);
}

// Round 12
// 66.678 us; speedup vs baseline: 1.2798x; 1.0353x over previous
//
#include <hip/hip_runtime.h>
#include <stdint.h>

#define DIM     300
#define NBATCH  4096
#define NSUP    64      // N*S = 2*32 support cols
#define KP      320     // B K padded to 10*32
#define LSTR    328     // A LDS row stride in ushorts (656 B, bank-staggered)
#define SMST    82      // padded sm tile x-stride (floats)
#define SMY     36      // per-channel y extent
#define GRID_G  256     // gemm blocks: 1 per CU
#define PPB     16      // batch panels per gemm block

typedef float f32x4 __attribute__((ext_vector_type(4)));
typedef short s16x8 __attribute__((ext_vector_type(8)));

static __device__ __forceinline__ unsigned bc(float x) { return __builtin_bit_cast(unsigned, x); }
static __device__ __forceinline__ float asf(unsigned u) { return __builtin_bit_cast(float, u); }
static __device__ __forceinline__ unsigned perm_hi(unsigned a, unsigned b) {
    return __builtin_amdgcn_perm(a, b, 0x07060302u);   // [a.hi16 : b.hi16]
}
static __device__ __forceinline__ unsigned short f2bf(float x) {   // RNE (prep only)
    unsigned u = bc(x);
    return (unsigned short)((u + 0x7FFFu + ((u >> 16) & 1u)) >> 16);
}
static __device__ __forceinline__ float bf2f(unsigned short h) { return asf((unsigned)h << 16); }

// ---------------- kernel 1: normalize support vectors -> bf16 hi/lo [64][320]
__global__ __launch_bounds__(64) void prep_kernel(
    const int* __restrict__ sidx, const float* __restrict__ emb,
    unsigned short* __restrict__ Bh, unsigned short* __restrict__ Bl) {
    const int j = blockIdx.x, l = threadIdx.x;
    const size_t tok = (size_t)sidx[j];
    const float* src = emb + tok * DIM;
    float e[5];
    #pragma unroll
    for (int c = 0; c < 5; ++c) {
        const int k = c * 64 + l;
        e[c] = (k < DIM) ? src[k] : 0.f;
    }
    float s = e[0]*e[0] + e[1]*e[1] + e[2]*e[2] + e[3]*e[3] + e[4]*e[4];
    #pragma unroll
    for (int m = 32; m >= 1; m >>= 1) s += __shfl_xor(s, m);
    const float rn = 1.f / fmaxf(sqrtf(s), 1e-8f);
    #pragma unroll
    for (int c = 0; c < 5; ++c) {
        const int k = c * 64 + l;
        const float v = (k < DIM) ? e[c] * rn : 0.f;
        const unsigned short h = f2bf(v);
        Bh[j * KP + k] = h;
        Bl[j * KP + k] = f2bf(v - bf2f(h));
    }
}

// ---------------- kernel 2: persistent gather-GEMM.
// B fragments live in VGPRs (loaded once from L2; 1 block/CU -> 256 VGPR budget).
// A double-buffered in LDS; inner loop touches ONLY LDS+regs (no vmcnt), so
// next-panel HBM gathers (issued before the loop, pinned) overlap it fully.
__global__ __launch_bounds__(512, 2) void gemm_kernel(
    const int* __restrict__ tokens, const float* __restrict__ emb,
    const unsigned short* __restrict__ Bh, const unsigned short* __restrict__ Bl,
    float* __restrict__ smG) {

    __shared__ __attribute__((aligned(16))) unsigned short AhL[2][32 * LSTR];  // 2x21 KB
    __shared__ __attribute__((aligned(16))) unsigned short AlL[2][32 * LSTR];  // 2x21 KB
    __shared__ __attribute__((aligned(16))) float norms[32];

    const int tid = threadIdx.x;
    const int l = tid & 63;
    const int w = tid >> 6;
    const int c = l & 15, hq = l >> 4;
    const int rb = (w >> 2) * 16;
    const int cg = w & 3;
    const int chn = cg >> 1, sb = (cg & 1) * 16;
    const int bbase = blockIdx.x * PPB;

    // ---- B fragments -> registers, once per block (L2-hot; 40 x b128 / thread)
    s16x8 rbh[10], rbl[10];
    {
        const unsigned short* pBh = Bh + (cg * 16 + c) * KP + hq * 8;
        const unsigned short* pBl = Bl + (cg * 16 + c) * KP + hq * 8;
        #pragma unroll
        for (int t = 0; t < 10; ++t) {
            rbh[t] = *(const s16x8*)(pBh + t * 32);
            rbl[t] = *(const s16x8*)(pBl + t * 32);
        }
    }

    // ---- one-time: zero A K-pad (k=300..327) in BOTH buffers
    if (tid < 448) {
        const int row = tid / 14, q = tid - 14 * row;   // 14 uints = 28 ushorts
        ((unsigned*)AhL[0])[row * 164 + 150 + q] = 0u;
        ((unsigned*)AlL[0])[row * 164 + 150 + q] = 0u;
        ((unsigned*)AhL[1])[row * 164 + 150 + q] = 0u;
        ((unsigned*)AlL[1])[row * 164 + 150 + q] = 0u;
    }

    // static staging chunk map: chunk ci = tid + 512*m over [32 rows][75 float4s]
    const int ci1 = tid + 512, ci2 = tid + 1024, ci3 = tid + 1536, ci4 = tid + 2048;
    const int r0 = tid / 75, j0 = tid - 75 * r0;
    const int r1 = ci1 / 75, j1 = ci1 - 75 * r1;
    const int r2 = ci2 / 75, j2 = ci2 - 75 * r2;
    const int r3 = ci3 / 75, j3 = ci3 - 75 * r3;
    const int r4 = ci4 / 75, j4 = ci4 - 75 * r4;
    const bool has4 = (ci4 < 2400);

    const int abase = (rb + c) * LSTR + hq * 8;

    float4 st0, st1, st2, st3, st4;

    #define ISSUE_GATHER(TB)                                                        \
    {                                                                               \
        st0 = *(const float4*)(emb + (size_t)tokens[(TB) + r0] * DIM + j0 * 4);     \
        st1 = *(const float4*)(emb + (size_t)tokens[(TB) + r1] * DIM + j1 * 4);     \
        st2 = *(const float4*)(emb + (size_t)tokens[(TB) + r2] * DIM + j2 * 4);     \
        st3 = *(const float4*)(emb + (size_t)tokens[(TB) + r3] * DIM + j3 * 4);     \
        if (has4) st4 = *(const float4*)(emb + (size_t)tokens[(TB) + r4] * DIM + j4 * 4); \
    }

    // convert one float4 chunk -> 4 bf16 hi + 4 bf16 lo, store to A LDS buffer
    #define STORE_CHUNK(AH, AL, ST, R, J)                                           \
    {                                                                               \
        const unsigned u0 = bc(ST.x) + 0x8000u, u1 = bc(ST.y) + 0x8000u;            \
        const unsigned u2 = bc(ST.z) + 0x8000u, u3 = bc(ST.w) + 0x8000u;            \
        const float q0f = ST.x - asf(u0 & 0xffff0000u);                             \
        const float q1f = ST.y - asf(u1 & 0xffff0000u);                             \
        const float q2f = ST.z - asf(u2 & 0xffff0000u);                             \
        const float q3f = ST.w - asf(u3 & 0xffff0000u);                             \
        *(uint2*)(&(AH)[(R) * LSTR + (J) * 4]) =                                    \
            uint2{perm_hi(u1, u0), perm_hi(u3, u2)};                                \
        *(uint2*)(&(AL)[(R) * LSTR + (J) * 4]) =                                    \
            uint2{perm_hi(bc(q1f) + 0x8000u, bc(q0f) + 0x8000u),                    \
                  perm_hi(bc(q3f) + 0x8000u, bc(q2f) + 0x8000u)};                   \
    }

    #define STAGE_ALL(AH, AL)                                                       \
    {                                                                               \
        STORE_CHUNK(AH, AL, st0, r0, j0); STORE_CHUNK(AH, AL, st1, r1, j1);         \
        STORE_CHUNK(AH, AL, st2, r2, j2); STORE_CHUNK(AH, AL, st3, r3, j3);         \
        if (has4) STORE_CHUNK(AH, AL, st4, r4, j4);                                 \
    }

    // prologue: gather + stage panel 0 into buffer 0
    ISSUE_GATHER(bbase * 32);
    STAGE_ALL(AhL[0], AlL[0]);
    __syncthreads();

    #pragma unroll 1
    for (int p = 0; p < PPB; ++p) {
        const int cur = p & 1, nxt = cur ^ 1;
        // issue next panel's gathers NOW; loop below never touches vmcnt
        if (p + 1 < PPB) ISSUE_GATHER((bbase + p + 1) * 32);
        __builtin_amdgcn_sched_barrier(0);

        // pure LDS+reg MFMA loop + Gram norms
        const unsigned short* pAh = AhL[cur];
        const unsigned short* pAl = AlL[cur];
        f32x4 q0 = {0,0,0,0}, q1 = {0,0,0,0}, q2 = {0,0,0,0};
        f32x4 gv = {0,0,0,0}, g2 = {0,0,0,0};
        #pragma unroll
        for (int t = 0; t < 10; ++t) {
            const s16x8 ah = *(const s16x8*)(pAh + abase + t * 32);
            const s16x8 al = *(const s16x8*)(pAl + abase + t * 32);
            q0 = __builtin_amdgcn_mfma_f32_16x16x32_bf16(ah, rbh[t], q0, 0, 0, 0);
            q1 = __builtin_amdgcn_mfma_f32_16x16x32_bf16(ah, rbl[t], q1, 0, 0, 0);
            q2 = __builtin_amdgcn_mfma_f32_16x16x32_bf16(al, rbh[t], q2, 0, 0, 0);
            gv = __builtin_amdgcn_mfma_f32_16x16x32_bf16(ah, ah, gv, 0, 0, 0);
            g2 = __builtin_amdgcn_mfma_f32_16x16x32_bf16(ah, al, g2, 0, 0, 0);
        }

        // diagonal lanes own |row rb+c|^2 (4 col-group waves race: identical values)
        if (hq == (c >> 2)) {
            const int q = c & 3;
            const float d1 = (q == 0) ? gv[0] : (q == 1) ? gv[1] : (q == 2) ? gv[2] : gv[3];
            const float d2 = (q == 0) ? g2[0] : (q == 1) ? g2[1] : (q == 2) ? g2[2] : g2[3];
            norms[rb + c] = d1 + 2.f * d2;
        }
        asm volatile("s_waitcnt lgkmcnt(0)" ::: "memory");   // intra-wave write->read
        const f32x4 n4 = *(const f32x4*)&norms[rb + hq * 4];
        float4 vv;
        #pragma unroll
        for (int q = 0; q < 4; ++q) {
            const float rn = __builtin_amdgcn_rcpf(
                fmaxf(__builtin_amdgcn_sqrtf(n4[q]), 1e-8f));
            ((float*)&vv)[q] = (q0[q] + q1[q] + q2[q]) * rn;
        }
        // coalesced sm store [b][ch][s][r]
        *(float4*)(smG + ((size_t)((bbase + p) * 2 + chn) * 32 + sb + c) * 32 + rb + hq * 4) = vv;

        if (p + 1 < PPB) {
            // gathers had the whole MFMA loop to land; stage into the OTHER buffer
            // (its readers finished at the end-of-panel-(p-1) barrier)
            STAGE_ALL(AhL[nxt], AlL[nxt]);
        }
        __syncthreads();    // next panel's A tiles ready
    }
    #undef STAGE_ALL
    #undef STORE_CHUNK
    #undef ISSUE_GATHER
}

// ---------------- kernel 3: tail per batch (softmax-gate + conv1 + conv2 + fc)
__global__ __launch_bounds__(256) void tail_kernel(
    const float* __restrict__ smG,
    const float* __restrict__ c1w, const float* __restrict__ c1b,
    const float* __restrict__ c2w, const float* __restrict__ c2b,
    const float* __restrict__ f2w, const float* __restrict__ f2b,
    const float* __restrict__ fcw, const float* __restrict__ fcb,
    float* __restrict__ out) {

    __shared__ __attribute__((aligned(16))) float smP[34 * SMST];  // [xp=r+1][ch][yp=s+1]
    __shared__ __attribute__((aligned(16))) float pl1P[2 * 17 * 18];
    __shared__ float scrP[8];    // [0..3]=se_w, [4..7]=sv_w

    const int tid = threadIdx.x;
    const int w = tid >> 6, l = tid & 63;
    const int b = blockIdx.x;

    // P0: zero smP + pl1 borders
    {
        const f32x4 z = {0.f, 0.f, 0.f, 0.f};
        #pragma unroll
        for (int i = 0; i < 3; ++i) {
            const int idx = i * 256 + tid;
            if (idx < 697) ((f32x4*)smP)[idx] = z;
        }
        if (tid >= 190) {
            const int z2 = tid - 190;
            const int ic = (z2 >= 33) ? 1 : 0;
            const int rm = z2 - 33 * ic;
            pl1P[ic * 306 + (rm < 17 ? rm : (rm - 16) * 18)] = 0.f;
        }
    }
    __syncthreads();

    // P1: load sm (coalesced) -> padded LDS + fused softmax partials
    {
        const float* src = smG + (size_t)b * 2048;
        float se = 0.f, sv = 0.f;
        #pragma unroll
        for (int h2 = 0; h2 < 2; ++h2) {
            const int f4 = tid * 2 + h2;            // waves 0-1: ch0; waves 2-3: ch1
            const float4 v = ((const float4*)src)[f4];
            const int base = f4 * 4;
            const int chn = base >> 10;
            const int s = (base >> 5) & 31;
            const int r = base & 31;
            float* dstp = &smP[(r + 1) * SMST + chn * SMY + (s + 1)];
            dstp[0] = v.x; dstp[SMST] = v.y; dstp[2 * SMST] = v.z; dstp[3 * SMST] = v.w;
            const float e0 = __expf(v.x), e1 = __expf(v.y);   // |v|<=1: no max-shift
            const float e2 = __expf(v.z), e3 = __expf(v.w);
            se += e0 + e1 + e2 + e3;
            sv = fmaf(e0, v.x, sv); sv = fmaf(e1, v.y, sv);
            sv = fmaf(e2, v.z, sv); sv = fmaf(e3, v.w, sv);
        }
        #pragma unroll
        for (int m = 32; m >= 1; m >>= 1) { se += __shfl_xor(se, m); sv += __shfl_xor(sv, m); }
        if (l == 0) { scrP[w] = se; scrP[4 + w] = sv; }
    }
    __syncthreads();

    // P2: conv1 (both oc per thread) + gate + relu + maxpool -> pl1P
    {
        const int ii = tid >> 4, jj = tid & 15;
        float pc0[4] = {0,0,0,0}, pc1[4] = {0,0,0,0};
        float pA0[4] = {0,0,0,0}, pA1[4] = {0,0,0,0};
        #pragma unroll
        for (int ic = 0; ic < 2; ++ic) {
            float p[4][4];
            #pragma unroll
            for (int a = 0; a < 4; ++a) {        // xp = 2jj+a, yp base 2ii
                const int off = (2 * jj + a) * SMST + ic * SMY + 2 * ii;
                const float2 v01 = *(const float2*)&smP[off];
                const float2 v23 = *(const float2*)&smP[off + 2];
                p[a][0] = v01.x; p[a][1] = v01.y; p[a][2] = v23.x; p[a][3] = v23.y;
            }
            #pragma unroll
            for (int py = 0; py < 2; ++py)
            #pragma unroll
            for (int px = 0; px < 2; ++px)
            #pragma unroll
            for (int dy = 0; dy < 3; ++dy)
            #pragma unroll
            for (int dx = 0; dx < 3; ++dx) {
                const float pv = p[px + dx][py + dy];
                const int pos = py * 2 + px;
                if (ic == 0) {
                    pc0[pos] = fmaf(c1w[0 * 9 + dy * 3 + dx], pv, pc0[pos]);
                    pc1[pos] = fmaf(c1w[2 * 9 + dy * 3 + dx], pv, pc1[pos]);
                } else {
                    pA0[pos] = fmaf(c1w[1 * 9 + dy * 3 + dx], pv, pA0[pos]);
                    pA1[pos] = fmaf(c1w[3 * 9 + dy * 3 + dx], pv, pA1[pos]);
                }
            }
        }
        const float p0 = (scrP[4] + scrP[5]) / (scrP[0] + scrP[1]);
        const float p1 = (scrP[6] + scrP[7]) / (scrP[2] + scrP[3]);
        const float gg0 = 1.f / (1.f + __expf(-(f2w[0] * p0 + f2w[1] * p1 + f2b[0])));
        const float gg1 = 1.f / (1.f + __expf(-(f2w[2] * p0 + f2w[3] * p1 + f2b[1])));
        const float b0 = c1b[0], b1 = c1b[1];
        float mx0 = 0.f, mx1 = 0.f;   // relu folded
        #pragma unroll
        for (int i = 0; i < 4; ++i) {
            mx0 = fmaxf(mx0, b0 + gg0 * pc0[i] + gg1 * pA0[i]);
            mx1 = fmaxf(mx1, b1 + gg0 * pc1[i] + gg1 * pA1[i]);
        }
        pl1P[0 * 306 + (ii + 1) * 18 + (jj + 1)] = mx0;
        pl1P[1 * 306 + (ii + 1) * 18 + (jj + 1)] = mx1;
    }
    __syncthreads();

    // P3: wave 0: conv2(2x2,pad1)+relu+avgpool2 + fc -> out
    if (w == 0) {
        float o0 = 0.f, o1 = 0.f;
        #pragma unroll
        for (int h = 0; h < 2; ++h) {
            const int o = h * 64 + l, oc2 = o >> 6, ii2 = (o >> 3) & 7, jj2 = o & 7;
            float sum = 0.f;
            #pragma unroll
            for (int py = 0; py < 2; ++py)
            #pragma unroll
            for (int px = 0; px < 2; ++px) {
                const int y = 2 * ii2 + py, x = 2 * jj2 + px;
                float acc = c2b[oc2];
                #pragma unroll
                for (int ic = 0; ic < 2; ++ic)
                #pragma unroll
                for (int dy = 0; dy < 2; ++dy)
                #pragma unroll
                for (int dx = 0; dx < 2; ++dx)
                    acc += c2w[((oc2 * 2 + ic) * 2 + dy) * 2 + dx] *
                           pl1P[ic * 306 + (y + dy) * 18 + (x + dx)];
                sum += fmaxf(acc, 0.f);
            }
            const float val = 0.25f * sum;
            o0 = fmaf(val, fcw[o], o0);
            o1 = fmaf(val, fcw[128 + o], o1);
        }
        #pragma unroll
        for (int m = 32; m >= 1; m >>= 1) { o0 += __shfl_xor(o0, m); o1 += __shfl_xor(o1, m); }
        if (l == 0) {
            out[b * 2 + 0] = fcb[0] + o0;
            out[b * 2 + 1] = fcb[1] + o1;
        }
    }
}

extern "C" void kernel_launch(void* const* d_in, const int* in_sizes, int n_in,
                              void* d_out, int out_size, void* d_ws, size_t ws_size,
                              hipStream_t stream) {
    const int* tokens = (const int*)d_in[0];
    const int* sidx   = (const int*)d_in[1];
    const float* emb  = (const float*)d_in[2];
    const float* c1w  = (const float*)d_in[3];
    const float* c1b  = (const float*)d_in[4];
    const float* c2w  = (const float*)d_in[5];
    const float* c2b  = (const float*)d_in[6];
    const float* f2w  = (const float*)d_in[7];
    const float* f2b  = (const float*)d_in[8];
    const float* fcw  = (const float*)d_in[9];
    const float* fcb  = (const float*)d_in[10];

    // ws layout: [sm f32 4096*2*32*32 = 32 MiB][Bh 40 KiB][Bl 40 KiB]
    float* smG = (float*)d_ws;
    unsigned short* Bh = (unsigned short*)((char*)d_ws + (size_t)NBATCH * 2048 * 4);
    unsigned short* Bl = Bh + NSUP * KP;

    prep_kernel<<<NSUP, 64, 0, stream>>>(sidx, emb, Bh, Bl);
    gemm_kernel<<<GRID_G, 512, 0, stream>>>(tokens, emb, Bh, Bl, smG);
    tail_kernel<<<NBATCH, 256, 0, stream>>>(smG, c1w, c1b, c2w, c2b,
                                            f2w, f2b, fcw, fcb, (float*)d_out);
}